// Round 1
// baseline (1702.038 us; speedup 1.0000x reference)
//
#include <hip/hip_runtime.h>
#include <hip/hip_bf16.h>

// Hard-concrete constants
#define BETA_INV 1.51515151515f   // 1/0.66
#define ZMG      1.2f             // ZETA - GAMMA
#define GAMMA_C  (-0.1f)

// ---------------------------------------------------------------------------
// Kernel 1: ft = x @ W + b   (x:[n,128], W:[128,128], b:[128])
// Tile: 32 rows x 128 cols per block of 256 threads.
// Thread (tc,tr): tc in [0,32) -> cols 4*tc..4*tc+3 (float4), tr in [0,8) ->
// rows 4*tr..4*tr+3.  W staged in LDS (64KB), x rows staged in LDS (16KB).
// ---------------------------------------------------------------------------
__global__ __launch_bounds__(256, 2) void gemm_ft(
    const float* __restrict__ x, const float* __restrict__ W,
    const float* __restrict__ bvec, float* __restrict__ ft, int n) {
  __shared__ float Wl[128 * 128];
  __shared__ float xs[32 * 128];
  const int tid = threadIdx.x;

  // stage W (16384 floats = 4096 float4)
  for (int i = tid; i < 4096; i += 256)
    ((float4*)Wl)[i] = ((const float4*)W)[i];

  const int row0 = blockIdx.x * 32;
  // stage 32 x-rows (1024 float4)
  for (int i = tid; i < 1024; i += 256) {
    int r = i >> 5, c4 = i & 31;
    int gr = row0 + r;
    float4 v = make_float4(0.f, 0.f, 0.f, 0.f);
    if (gr < n) v = ((const float4*)(x + (size_t)gr * 128))[c4];
    ((float4*)xs)[i] = v;
  }
  __syncthreads();

  const int tc = tid & 31;   // col group
  const int tr = tid >> 5;   // row group (0..7)
  float4 bb = ((const float4*)bvec)[tc];
  float4 acc[4];
#pragma unroll
  for (int r = 0; r < 4; ++r) acc[r] = bb;

#pragma unroll 4
  for (int k = 0; k < 128; ++k) {
    float4 w = ((const float4*)(Wl + k * 128))[tc];
    float xv[4];
#pragma unroll
    for (int r = 0; r < 4; ++r) xv[r] = xs[(4 * tr + r) * 128 + k];
#pragma unroll
    for (int r = 0; r < 4; ++r) {
      acc[r].x += xv[r] * w.x;
      acc[r].y += xv[r] * w.y;
      acc[r].z += xv[r] * w.z;
      acc[r].w += xv[r] * w.w;
    }
  }

#pragma unroll
  for (int r = 0; r < 4; ++r) {
    int gr = row0 + 4 * tr + r;
    if (gr < n) ((float4*)(ft + (size_t)gr * 128))[tc] = acc[r];
  }
}

// ---------------------------------------------------------------------------
// Kernel 2: a1[i] = ft[i,:] . attn_l ; a2[i] = ft[i,:] . attn_r
// One wave (64 lanes) per row, float2 per lane.
// ---------------------------------------------------------------------------
__global__ __launch_bounds__(256) void attn_proj(
    const float* __restrict__ ft, const float* __restrict__ attn_l,
    const float* __restrict__ attn_r, float* __restrict__ a1,
    float* __restrict__ a2, int n) {
  int lane = threadIdx.x & 63;
  int row = (int)((blockIdx.x * blockDim.x + threadIdx.x) >> 6);
  if (row >= n) return;
  float2 f = *(const float2*)(ft + (size_t)row * 128 + lane * 2);
  float2 al = *(const float2*)(attn_l + lane * 2);
  float2 ar = *(const float2*)(attn_r + lane * 2);
  float s1 = f.x * al.x + f.y * al.y;
  float s2 = f.x * ar.x + f.y * ar.y;
#pragma unroll
  for (int off = 32; off; off >>= 1) {
    s1 += __shfl_down(s1, off);
    s2 += __shfl_down(s2, off);
  }
  if (lane == 0) {
    a1[row] = s1;
    a2[row] = s2;
  }
}

// ---------------------------------------------------------------------------
// Kernel 3: per-edge hard-concrete gate + z[dst] segment sum (atomics)
// ---------------------------------------------------------------------------
__global__ __launch_bounds__(256) void edge_gate(
    const int* __restrict__ src, const int* __restrict__ dst,
    const float* __restrict__ a1, const float* __restrict__ a2,
    const float* __restrict__ bias, float* __restrict__ a,
    float* __restrict__ z, int E) {
  float bl = bias[0];
  int stride = gridDim.x * blockDim.x;
  for (int e = blockIdx.x * blockDim.x + threadIdx.x; e < E; e += stride) {
    int s = src[e], d = dst[e];
    float val = 1.0f;
    if (s != d) {
      float logit = (a1[s] + a2[d] + bl) * BETA_INV;
      float sg = 1.0f / (1.0f + __expf(-logit));
      val = sg * ZMG + GAMMA_C;
      val = fminf(fmaxf(val, 0.0f), 1.0f);
    }
    a[e] = val;
    atomicAdd(&z[d], val);
  }
}

// ---------------------------------------------------------------------------
// Kernel 4: out[dst] += (a[e]/z[dst]) * ft[src]   (wave per edge, float2/lane)
// ---------------------------------------------------------------------------
__global__ __launch_bounds__(256) void aggregate(
    const int* __restrict__ src, const int* __restrict__ dst,
    const float* __restrict__ a, const float* __restrict__ z,
    const float* __restrict__ ft, float* __restrict__ out, int E) {
  int lane = threadIdx.x & 63;
  int wid = (int)((blockIdx.x * blockDim.x + threadIdx.x) >> 6);
  int nw = (gridDim.x * blockDim.x) >> 6;
  for (int e = wid; e < E; e += nw) {
    int s = src[e], d = dst[e];
    float w = a[e] / z[d];
    float2 v = *(const float2*)(ft + (size_t)s * 128 + lane * 2);
    atomicAdd(&out[(size_t)d * 128 + lane * 2], w * v.x);
    atomicAdd(&out[(size_t)d * 128 + lane * 2 + 1], w * v.y);
  }
}

// ---------------------------------------------------------------------------
extern "C" void kernel_launch(void* const* d_in, const int* in_sizes, int n_in,
                              void* d_out, int out_size, void* d_ws,
                              size_t ws_size, hipStream_t stream) {
  const float* x      = (const float*)d_in[0];
  const float* W      = (const float*)d_in[1];
  const float* b      = (const float*)d_in[2];
  const float* attn_l = (const float*)d_in[3];
  const float* attn_r = (const float*)d_in[4];
  const float* bias   = (const float*)d_in[5];
  const int*   src    = (const int*)d_in[6];
  const int*   dst    = (const int*)d_in[7];

  const int n = in_sizes[0] / 128;   // 100000
  const int E = in_sizes[6];         // 1700000

  // workspace layout (fp32): ft[n*128] | a1[n] | a2[n] | z[n] | a[E]
  float* ft = (float*)d_ws;
  float* a1 = ft + (size_t)n * 128;
  float* a2 = a1 + n;
  float* z  = a2 + n;
  float* a  = z + n;

  hipMemsetAsync(z, 0, (size_t)n * sizeof(float), stream);
  hipMemsetAsync(d_out, 0, (size_t)out_size * sizeof(float), stream);

  gemm_ft<<<(n + 31) / 32, 256, 0, stream>>>(x, W, b, ft, n);
  attn_proj<<<(n * 64 + 255) / 256, 256, 0, stream>>>(ft, attn_l, attn_r, a1,
                                                      a2, n);
  edge_gate<<<2048, 256, 0, stream>>>(src, dst, a1, a2, bias, a, z, E);
  aggregate<<<2048, 256, 0, stream>>>(src, dst, a, z, ft, (float*)d_out, E);
}

// Round 2
// 649.151 us; speedup vs baseline: 2.6219x; 2.6219x over previous
//
#include <hip/hip_runtime.h>
#include <hip/hip_bf16.h>

// Hard-concrete constants
#define BETA_INV 1.51515151515f   // 1/0.66
#define ZMG      1.2f             // ZETA - GAMMA
#define GAMMA_C  (-0.1f)

// ---------------------------------------------------------------------------
// Kernel 1: ft = x @ W + b, fused with a1 = ft.attn_l, a2 = ft.attn_r
// 32 rows x 128 cols per block of 256 threads. W in LDS (64KB), x tile (16KB).
// Thread (tr,tc): tc in [0,32) -> col group (float4), tr in [0,8) -> 4 rows.
// ---------------------------------------------------------------------------
__global__ __launch_bounds__(256, 2) void gemm_ft(
    const float* __restrict__ x, const float* __restrict__ W,
    const float* __restrict__ bvec, const float* __restrict__ attn_l,
    const float* __restrict__ attn_r, float* __restrict__ ft,
    float* __restrict__ a1, float* __restrict__ a2, int n) {
  __shared__ float Wl[128 * 128];
  __shared__ float xs[32 * 128];
  const int tid = threadIdx.x;

  for (int i = tid; i < 4096; i += 256)
    ((float4*)Wl)[i] = ((const float4*)W)[i];

  const int row0 = blockIdx.x * 32;
  for (int i = tid; i < 1024; i += 256) {
    int r = i >> 5, c4 = i & 31;
    int gr = row0 + r;
    float4 v = make_float4(0.f, 0.f, 0.f, 0.f);
    if (gr < n) v = ((const float4*)(x + (size_t)gr * 128))[c4];
    ((float4*)xs)[i] = v;
  }
  __syncthreads();

  const int tc = tid & 31;
  const int tr = tid >> 5;
  float4 bb = ((const float4*)bvec)[tc];
  float4 acc[4];
#pragma unroll
  for (int r = 0; r < 4; ++r) acc[r] = bb;

#pragma unroll 4
  for (int k = 0; k < 128; ++k) {
    float4 w = ((const float4*)(Wl + k * 128))[tc];
    float xv[4];
#pragma unroll
    for (int r = 0; r < 4; ++r) xv[r] = xs[(4 * tr + r) * 128 + k];
#pragma unroll
    for (int r = 0; r < 4; ++r) {
      acc[r].x += xv[r] * w.x;
      acc[r].y += xv[r] * w.y;
      acc[r].z += xv[r] * w.z;
      acc[r].w += xv[r] * w.w;
    }
  }

  float4 al = ((const float4*)attn_l)[tc];
  float4 ar = ((const float4*)attn_r)[tc];
#pragma unroll
  for (int r = 0; r < 4; ++r) {
    int gr = row0 + 4 * tr + r;
    if (gr < n) ((float4*)(ft + (size_t)gr * 128))[tc] = acc[r];
    float s1 = acc[r].x * al.x + acc[r].y * al.y + acc[r].z * al.z +
               acc[r].w * al.w;
    float s2 = acc[r].x * ar.x + acc[r].y * ar.y + acc[r].z * ar.z +
               acc[r].w * ar.w;
    // reduce across the 32 tc lanes (xor offsets stay within the half-wave)
#pragma unroll
    for (int off = 16; off; off >>= 1) {
      s1 += __shfl_xor(s1, off);
      s2 += __shfl_xor(s2, off);
    }
    if (tc == 0 && gr < n) {
      a1[gr] = s1;
      a2[gr] = s2;
    }
  }
}

// ---------------------------------------------------------------------------
// Kernel 2: per-edge gate value + z[dst] (float atomic) + deg[dst] histogram
// ---------------------------------------------------------------------------
__global__ __launch_bounds__(256) void edge_gate(
    const int* __restrict__ src, const int* __restrict__ dst,
    const float* __restrict__ a1, const float* __restrict__ a2,
    const float* __restrict__ bias, float* __restrict__ a,
    float* __restrict__ z, int* __restrict__ deg, int E) {
  float bl = bias[0];
  int e = blockIdx.x * blockDim.x + threadIdx.x;
  if (e >= E) return;
  int s = src[e], d = dst[e];
  float val = 1.0f;
  if (s != d) {
    float logit = (a1[s] + a2[d] + bl) * BETA_INV;
    float sg = 1.0f / (1.0f + __expf(-logit));
    val = sg * ZMG + GAMMA_C;
    val = fminf(fmaxf(val, 0.0f), 1.0f);
  }
  a[e] = val;
  atomicAdd(&z[d], val);
  atomicAdd(&deg[d], 1);
}

// ---------------------------------------------------------------------------
// Scan pipeline: deg[n] -> rowptr[n] (exclusive start offsets)
// ---------------------------------------------------------------------------
__global__ __launch_bounds__(256) void scan_partial(const int* __restrict__ deg,
                                                    int* __restrict__ part,
                                                    int n) {
  __shared__ int sd[256];
  int base = blockIdx.x * 1024;
  int s = 0;
  for (int i = threadIdx.x; i < 1024; i += 256) {
    int idx = base + i;
    s += (idx < n) ? deg[idx] : 0;
  }
  sd[threadIdx.x] = s;
  __syncthreads();
  for (int off = 128; off; off >>= 1) {
    if (threadIdx.x < off) sd[threadIdx.x] += sd[threadIdx.x + off];
    __syncthreads();
  }
  if (threadIdx.x == 0) part[blockIdx.x] = sd[0];
}

__global__ __launch_bounds__(1024) void scan_top(int* __restrict__ part,
                                                 int B) {
  __shared__ int sd[1024];
  int t = threadIdx.x;
  int mine = (t < B) ? part[t] : 0;
  sd[t] = mine;
  __syncthreads();
  for (int off = 1; off < 1024; off <<= 1) {
    int v = (t >= off) ? sd[t - off] : 0;
    __syncthreads();
    sd[t] += v;
    __syncthreads();
  }
  if (t < B) part[t] = sd[t] - mine;  // exclusive
}

__global__ __launch_bounds__(256) void scan_write(const int* __restrict__ deg,
                                                  const int* __restrict__ part,
                                                  int* __restrict__ rowptr,
                                                  int n) {
  __shared__ int tsum[256];
  int base = blockIdx.x * 1024;
  int v[4];
  int s = 0;
#pragma unroll
  for (int j = 0; j < 4; ++j) {
    int idx = base + threadIdx.x * 4 + j;
    v[j] = (idx < n) ? deg[idx] : 0;
    s += v[j];
  }
  tsum[threadIdx.x] = s;
  __syncthreads();
  for (int off = 1; off < 256; off <<= 1) {
    int t = (threadIdx.x >= (unsigned)off) ? tsum[threadIdx.x - off] : 0;
    __syncthreads();
    tsum[threadIdx.x] += t;
    __syncthreads();
  }
  int excl = tsum[threadIdx.x] - s + part[blockIdx.x];
#pragma unroll
  for (int j = 0; j < 4; ++j) {
    int idx = base + threadIdx.x * 4 + j;
    if (idx < n) {
      rowptr[idx] = excl;
      excl += v[j];
    }
  }
}

// ---------------------------------------------------------------------------
// Scatter: eidx[pos] = e, pos = rowptr[d]++ (rowptr mutates into end offsets)
// ---------------------------------------------------------------------------
__global__ __launch_bounds__(256) void scatter_edges(const int* __restrict__ dst,
                                                     int* __restrict__ rowptr,
                                                     int* __restrict__ eidx,
                                                     int E) {
  int e = blockIdx.x * blockDim.x + threadIdx.x;
  if (e >= E) return;
  int d = dst[e];
  int pos = atomicAdd(&rowptr[d], 1);
  eidx[pos] = e;
}

// ---------------------------------------------------------------------------
// Aggregate (atomic-free): one wave per dst node, float2 per lane in regs.
// Segment of node v = [v==0 ? 0 : rowend[v-1], rowend[v])  (post-scatter).
// ---------------------------------------------------------------------------
__global__ __launch_bounds__(256) void aggregate_csr(
    const int* __restrict__ src, const int* __restrict__ rowend,
    const int* __restrict__ eidx, const float* __restrict__ a,
    const float* __restrict__ z, const float* __restrict__ ft,
    float* __restrict__ out, int n) {
  int lane = threadIdx.x & 63;
  int node = (int)((blockIdx.x * blockDim.x + threadIdx.x) >> 6);
  if (node >= n) return;
  int s1 = rowend[node];
  int s0 = (node == 0) ? 0 : rowend[node - 1];
  float zinv = 1.0f / z[node];
  const float* ftl = ft + lane * 2;
  float accx = 0.f, accy = 0.f;
  for (int base = s0; base < s1; base += 64) {
    int cnt = min(64, s1 - base);
    int sidx = 0;
    float w = 0.f;
    if (lane < cnt) {
      int e = eidx[base + lane];
      sidx = src[e];
      w = a[e] * zinv;
    }
    for (int j = 0; j < cnt; ++j) {
      int sj = __shfl(sidx, j);
      float wj = __shfl(w, j);
      float2 v = *(const float2*)(ftl + (size_t)sj * 128);
      accx += wj * v.x;
      accy += wj * v.y;
    }
  }
  float2 r = make_float2(accx, accy);
  *(float2*)(out + (size_t)node * 128 + lane * 2) = r;
}

// ---------------------------------------------------------------------------
extern "C" void kernel_launch(void* const* d_in, const int* in_sizes, int n_in,
                              void* d_out, int out_size, void* d_ws,
                              size_t ws_size, hipStream_t stream) {
  const float* x      = (const float*)d_in[0];
  const float* W      = (const float*)d_in[1];
  const float* b      = (const float*)d_in[2];
  const float* attn_l = (const float*)d_in[3];
  const float* attn_r = (const float*)d_in[4];
  const float* bias   = (const float*)d_in[5];
  const int*   src    = (const int*)d_in[6];
  const int*   dst    = (const int*)d_in[7];

  const int n = in_sizes[0] / 128;   // 100000
  const int E = in_sizes[6];         // 1700000
  const int B = (n + 1023) / 1024;   // scan blocks (98)

  // workspace layout: ft[n*128] | a1[n] | a2[n] | z[n] | deg[n] | part[1024]
  //                   | rowptr[n] | a[E] | eidx[E]
  float* ft     = (float*)d_ws;
  float* a1     = ft + (size_t)n * 128;
  float* a2     = a1 + n;
  float* z      = a2 + n;
  int*   deg    = (int*)(z + n);
  int*   part   = deg + n;
  int*   rowptr = part + 1024;
  float* a      = (float*)(rowptr + n);
  int*   eidx   = (int*)(a + E);

  // zero z and deg in one shot (adjacent)
  hipMemsetAsync(z, 0, (size_t)2 * n * sizeof(float), stream);

  gemm_ft<<<(n + 31) / 32, 256, 0, stream>>>(x, W, b, attn_l, attn_r, ft, a1,
                                             a2, n);
  edge_gate<<<(E + 255) / 256, 256, 0, stream>>>(src, dst, a1, a2, bias, a, z,
                                                 deg, E);
  scan_partial<<<B, 256, 0, stream>>>(deg, part, n);
  scan_top<<<1, 1024, 0, stream>>>(part, B);
  scan_write<<<B, 256, 0, stream>>>(deg, part, rowptr, n);
  scatter_edges<<<(E + 255) / 256, 256, 0, stream>>>(dst, rowptr, eidx, E);
  aggregate_csr<<<((size_t)n * 64 + 255) / 256, 256, 0, stream>>>(
      src, rowptr, eidx, a, z, ft, (float*)d_out, n);
}

// Round 6
// 526.257 us; speedup vs baseline: 3.2342x; 1.2335x over previous
//
#include <hip/hip_runtime.h>
#include <hip/hip_bf16.h>

// Hard-concrete constants
#define BETA_INV 1.51515151515f   // 1/0.66
#define ZMG      1.2f             // ZETA - GAMMA
#define GAMMA_C  (-0.1f)

// fp32 -> bf16 (round-to-nearest-even), as raw ushort bits
__device__ __forceinline__ ushort f32_to_bf16(float f) {
  unsigned u = __float_as_uint(f);
  u += 0x7fffu + ((u >> 16) & 1u);
  return (ushort)(u >> 16);
}

// ---------------------------------------------------------------------------
// Kernel 1: ft = x @ W + b (written as bf16), fused a1 = ft.attn_l, a2 = ft.attn_r
// 32 rows x 128 cols per block of 256 threads. W in LDS (64KB), xs padded
// stride 132 so float4 k-reads land in distinct banks.
// ---------------------------------------------------------------------------
__global__ __launch_bounds__(256, 2) void gemm_ft(
    const float* __restrict__ x, const float* __restrict__ W,
    const float* __restrict__ bvec, const float* __restrict__ attn_l,
    const float* __restrict__ attn_r, ushort* __restrict__ ftb,
    float* __restrict__ a1, float* __restrict__ a2, int n) {
  __shared__ float Wl[128 * 128];
  __shared__ float xs[32 * 132];
  const int tid = threadIdx.x;

  for (int i = tid; i < 4096; i += 256)
    ((float4*)Wl)[i] = ((const float4*)W)[i];

  const int row0 = blockIdx.x * 32;
  for (int i = tid; i < 1024; i += 256) {
    int r = i >> 5, c4 = i & 31;
    int gr = row0 + r;
    float4 v = make_float4(0.f, 0.f, 0.f, 0.f);
    if (gr < n) v = ((const float4*)(x + (size_t)gr * 128))[c4];
    *(float4*)(xs + r * 132 + c4 * 4) = v;
  }
  __syncthreads();

  const int tc = tid & 31;   // col group (4 cols)
  const int tr = tid >> 5;   // row group (4 rows)
  float4 bb = ((const float4*)bvec)[tc];
  float4 acc[4];
#pragma unroll
  for (int r = 0; r < 4; ++r) acc[r] = bb;

#pragma unroll 2
  for (int k4 = 0; k4 < 32; ++k4) {
    float4 w0 = ((const float4*)(Wl + (k4 * 4 + 0) * 128))[tc];
    float4 w1 = ((const float4*)(Wl + (k4 * 4 + 1) * 128))[tc];
    float4 w2 = ((const float4*)(Wl + (k4 * 4 + 2) * 128))[tc];
    float4 w3 = ((const float4*)(Wl + (k4 * 4 + 3) * 128))[tc];
#pragma unroll
    for (int r = 0; r < 4; ++r) {
      float4 xv = *(const float4*)(xs + (4 * tr + r) * 132 + k4 * 4);
      acc[r].x += xv.x * w0.x + xv.y * w1.x + xv.z * w2.x + xv.w * w3.x;
      acc[r].y += xv.x * w0.y + xv.y * w1.y + xv.z * w2.y + xv.w * w3.y;
      acc[r].z += xv.x * w0.z + xv.y * w1.z + xv.z * w2.z + xv.w * w3.z;
      acc[r].w += xv.x * w0.w + xv.y * w1.w + xv.z * w2.w + xv.w * w3.w;
    }
  }

  float4 al = ((const float4*)attn_l)[tc];
  float4 ar = ((const float4*)attn_r)[tc];
#pragma unroll
  for (int r = 0; r < 4; ++r) {
    int gr = row0 + 4 * tr + r;
    if (gr < n) {
      ushort4 h;
      h.x = f32_to_bf16(acc[r].x);
      h.y = f32_to_bf16(acc[r].y);
      h.z = f32_to_bf16(acc[r].z);
      h.w = f32_to_bf16(acc[r].w);
      *(ushort4*)(ftb + (size_t)gr * 128 + tc * 4) = h;
    }
    float s1 = acc[r].x * al.x + acc[r].y * al.y + acc[r].z * al.z +
               acc[r].w * al.w;
    float s2 = acc[r].x * ar.x + acc[r].y * ar.y + acc[r].z * ar.z +
               acc[r].w * ar.w;
#pragma unroll
    for (int off = 16; off; off >>= 1) {
      s1 += __shfl_xor(s1, off);
      s2 += __shfl_xor(s2, off);
    }
    if (tc == 0 && gr < n) {
      a1[gr] = s1;
      a2[gr] = s2;
    }
  }
}

// ---------------------------------------------------------------------------
// Kernel 2: dst histogram
// ---------------------------------------------------------------------------
__global__ __launch_bounds__(256) void hist_deg(const int* __restrict__ dst,
                                                int* __restrict__ deg, int E) {
  int e = blockIdx.x * blockDim.x + threadIdx.x;
  if (e < E) atomicAdd(&deg[dst[e]], 1);
}

// ---------------------------------------------------------------------------
// Scan pipeline: deg[n] -> rowptr[n] (exclusive start offsets)
// ---------------------------------------------------------------------------
__global__ __launch_bounds__(256) void scan_partial(const int* __restrict__ deg,
                                                    int* __restrict__ part,
                                                    int n) {
  __shared__ int sd[256];
  int base = blockIdx.x * 1024;
  int s = 0;
  for (int i = threadIdx.x; i < 1024; i += 256) {
    int idx = base + i;
    s += (idx < n) ? deg[idx] : 0;
  }
  sd[threadIdx.x] = s;
  __syncthreads();
  for (int off = 128; off; off >>= 1) {
    if (threadIdx.x < off) sd[threadIdx.x] += sd[threadIdx.x + off];
    __syncthreads();
  }
  if (threadIdx.x == 0) part[blockIdx.x] = sd[0];
}

__global__ __launch_bounds__(1024) void scan_top(int* __restrict__ part,
                                                 int B) {
  __shared__ int sd[1024];
  int t = threadIdx.x;
  int mine = (t < B) ? part[t] : 0;
  sd[t] = mine;
  __syncthreads();
  for (int off = 1; off < 1024; off <<= 1) {
    int v = (t >= off) ? sd[t - off] : 0;
    __syncthreads();
    sd[t] += v;
    __syncthreads();
  }
  if (t < B) part[t] = sd[t] - mine;  // exclusive
}

__global__ __launch_bounds__(256) void scan_write(const int* __restrict__ deg,
                                                  const int* __restrict__ part,
                                                  int* __restrict__ rowptr,
                                                  int n) {
  __shared__ int tsum[256];
  int base = blockIdx.x * 1024;
  int v[4];
  int s = 0;
#pragma unroll
  for (int j = 0; j < 4; ++j) {
    int idx = base + threadIdx.x * 4 + j;
    v[j] = (idx < n) ? deg[idx] : 0;
    s += v[j];
  }
  tsum[threadIdx.x] = s;
  __syncthreads();
  for (int off = 1; off < 256; off <<= 1) {
    int t = (threadIdx.x >= (unsigned)off) ? tsum[threadIdx.x - off] : 0;
    __syncthreads();
    tsum[threadIdx.x] += t;
    __syncthreads();
  }
  int excl = tsum[threadIdx.x] - s + part[blockIdx.x];
#pragma unroll
  for (int j = 0; j < 4; ++j) {
    int idx = base + threadIdx.x * 4 + j;
    if (idx < n) {
      rowptr[idx] = excl;
      excl += v[j];
    }
  }
}

// ---------------------------------------------------------------------------
// Kernel 3: gate + z[dst] + scatter (src, val) pairs grouped by dst.
// rowptr mutates into end offsets.
// ---------------------------------------------------------------------------
__global__ __launch_bounds__(256) void edge_gate_scatter(
    const int* __restrict__ src, const int* __restrict__ dst,
    const float* __restrict__ a1, const float* __restrict__ a2,
    const float* __restrict__ bias, float* __restrict__ z,
    int* __restrict__ rowptr, int2* __restrict__ pairs, int E) {
  int e = blockIdx.x * blockDim.x + threadIdx.x;
  if (e >= E) return;
  int s = src[e], d = dst[e];
  float val = 1.0f;
  if (s != d) {
    float logit = (a1[s] + a2[d] + bias[0]) * BETA_INV;
    float sg = 1.0f / (1.0f + __expf(-logit));
    val = fminf(fmaxf(sg * ZMG + GAMMA_C, 0.0f), 1.0f);
  }
  atomicAdd(&z[d], val);
  int pos = atomicAdd(&rowptr[d], 1);
  pairs[pos] = make_int2(s, __float_as_int(val));
}

// ---------------------------------------------------------------------------
// Kernel 4: out[v] = sum w_e * ftb[src_e]  — one wave per node.
// 16 lanes x uint4 cover one 256B bf16 row; 4 edges processed per step.
// acc[i] corresponds to output element li*8 + i (in order).
// ---------------------------------------------------------------------------
__global__ __launch_bounds__(256) void aggregate_bf16(
    const int2* __restrict__ pairs, const int* __restrict__ rowend,
    const float* __restrict__ z, const ushort* __restrict__ ftb,
    float* __restrict__ out, int n) {
  int lane = threadIdx.x & 63;
  int node = (int)((blockIdx.x * blockDim.x + threadIdx.x) >> 6);
  if (node >= n) return;
  int e1 = rowend[node];
  int e0 = (node == 0) ? 0 : rowend[node - 1];
  float zinv = 1.0f / z[node];
  int g = lane >> 4, li = lane & 15;
  float acc[8] = {0.f, 0.f, 0.f, 0.f, 0.f, 0.f, 0.f, 0.f};

  for (int base = e0; base < e1; base += 64) {
    int cnt = min(64, e1 - base);
    int sidx = 0;
    float w = 0.f;
    if (lane < cnt) {
      int2 p = pairs[base + lane];
      sidx = p.x;
      w = __int_as_float(p.y) * zinv;
    }
    int nj = (cnt + 3) >> 2;
    for (int j = 0; j < nj; ++j) {
      int idx = 4 * j + g;
      int sj = __shfl(sidx, idx);
      float wj = __shfl(w, idx);   // wj == 0 for idx >= cnt (w zeroed)
      uint4 v = ((const uint4*)(ftb + (size_t)sj * 128))[li];
      acc[0] += wj * __uint_as_float(v.x << 16);          // elem li*8+0
      acc[1] += wj * __uint_as_float(v.x & 0xffff0000u);  // elem li*8+1
      acc[2] += wj * __uint_as_float(v.y << 16);
      acc[3] += wj * __uint_as_float(v.y & 0xffff0000u);
      acc[4] += wj * __uint_as_float(v.z << 16);
      acc[5] += wj * __uint_as_float(v.z & 0xffff0000u);
      acc[6] += wj * __uint_as_float(v.w << 16);
      acc[7] += wj * __uint_as_float(v.w & 0xffff0000u);
    }
  }
#pragma unroll
  for (int i = 0; i < 8; ++i) {
    acc[i] += __shfl_xor(acc[i], 16);
    acc[i] += __shfl_xor(acc[i], 32);
  }
  if (lane < 16) {
    float4* op = (float4*)(out + (size_t)node * 128 + li * 8);
    op[0] = make_float4(acc[0], acc[1], acc[2], acc[3]);
    op[1] = make_float4(acc[4], acc[5], acc[6], acc[7]);
  }
}

// ---------------------------------------------------------------------------
extern "C" void kernel_launch(void* const* d_in, const int* in_sizes, int n_in,
                              void* d_out, int out_size, void* d_ws,
                              size_t ws_size, hipStream_t stream) {
  const float* x      = (const float*)d_in[0];
  const float* W      = (const float*)d_in[1];
  const float* b      = (const float*)d_in[2];
  const float* attn_l = (const float*)d_in[3];
  const float* attn_r = (const float*)d_in[4];
  const float* bias   = (const float*)d_in[5];
  const int*   src    = (const int*)d_in[6];
  const int*   dst    = (const int*)d_in[7];

  const int n = in_sizes[0] / 128;   // 100000
  const int E = in_sizes[6];         // 1700000
  const int B = (n + 1023) / 1024;

  // workspace: ftb bf16[n*128] | a1[n] | a2[n] | z[n] | deg[n] | part[1024]
  //            | rowptr[n] | pairs int2[E]
  ushort* ftb   = (ushort*)d_ws;
  float* a1     = (float*)(ftb + (size_t)n * 128);
  float* a2     = a1 + n;
  float* z      = a2 + n;
  int*   deg    = (int*)(z + n);
  int*   part   = deg + n;
  int*   rowptr = part + 1024;
  int2*  pairs  = (int2*)(rowptr + n);

  (void)hipMemsetAsync(z, 0, (size_t)2 * n * sizeof(float), stream);  // z + deg

  gemm_ft<<<(n + 31) / 32, 256, 0, stream>>>(x, W, b, attn_l, attn_r, ftb, a1,
                                             a2, n);
  hist_deg<<<(E + 255) / 256, 256, 0, stream>>>(dst, deg, E);
  scan_partial<<<B, 256, 0, stream>>>(deg, part, n);
  scan_top<<<1, 1024, 0, stream>>>(part, B);
  scan_write<<<B, 256, 0, stream>>>(deg, part, rowptr, n);
  edge_gate_scatter<<<(E + 255) / 256, 256, 0, stream>>>(src, dst, a1, a2, bias,
                                                         z, rowptr, pairs, E);
  aggregate_bf16<<<((size_t)n * 64 + 255) / 256, 256, 0, stream>>>(
      pairs, rowptr, z, ftb, (float*)d_out, n);
}

// Round 7
// 388.168 us; speedup vs baseline: 4.3848x; 1.3557x over previous
//
#include <hip/hip_runtime.h>
#include <hip/hip_bf16.h>

// Hard-concrete constants
#define BETA_INV 1.51515151515f   // 1/0.66
#define ZMG      1.2f             // ZETA - GAMMA
#define GAMMA_C  (-0.1f)

#define WQ_SCALE 32767.0f
#define WQ_INV   (1.0f / 32767.0f)

// fp32 -> bf16 (round-to-nearest-even), as raw ushort bits
__device__ __forceinline__ ushort f32_to_bf16(float f) {
  unsigned u = __float_as_uint(f);
  u += 0x7fffu + ((u >> 16) & 1u);
  return (ushort)(u >> 16);
}

// ---------------------------------------------------------------------------
// Kernel 1: ft = x @ W + b (written as bf16), fused a1 = ft.attn_l, a2 = ft.attn_r
// 32 rows x 128 cols per block of 256 threads. Only the x tile is staged in
// LDS (17 KB); W (64 KB) is read from global — it is L2-resident and
// broadcast across blocks. This lifts occupancy from 1 block/CU to 3.
// ---------------------------------------------------------------------------
__global__ __launch_bounds__(256, 3) void gemm_ft(
    const float* __restrict__ x, const float* __restrict__ W,
    const float* __restrict__ bvec, const float* __restrict__ attn_l,
    const float* __restrict__ attn_r, ushort* __restrict__ ftb,
    float* __restrict__ a1, float* __restrict__ a2, int n) {
  __shared__ float xs[32 * 132];
  const int tid = threadIdx.x;

  const int row0 = blockIdx.x * 32;
  for (int i = tid; i < 1024; i += 256) {
    int r = i >> 5, c4 = i & 31;
    int gr = row0 + r;
    float4 v = make_float4(0.f, 0.f, 0.f, 0.f);
    if (gr < n) v = ((const float4*)(x + (size_t)gr * 128))[c4];
    *(float4*)(xs + r * 132 + c4 * 4) = v;
  }
  __syncthreads();

  const int tc = tid & 31;   // col group (4 cols)
  const int tr = tid >> 5;   // row group (4 rows)
  float4 bb = ((const float4*)bvec)[tc];
  float4 acc[4];
#pragma unroll
  for (int r = 0; r < 4; ++r) acc[r] = bb;

#pragma unroll 2
  for (int k4 = 0; k4 < 32; ++k4) {
    float4 w0 = ((const float4*)(W + (k4 * 4 + 0) * 128))[tc];
    float4 w1 = ((const float4*)(W + (k4 * 4 + 1) * 128))[tc];
    float4 w2 = ((const float4*)(W + (k4 * 4 + 2) * 128))[tc];
    float4 w3 = ((const float4*)(W + (k4 * 4 + 3) * 128))[tc];
#pragma unroll
    for (int r = 0; r < 4; ++r) {
      float4 xv = *(const float4*)(xs + (4 * tr + r) * 132 + k4 * 4);
      acc[r].x += xv.x * w0.x + xv.y * w1.x + xv.z * w2.x + xv.w * w3.x;
      acc[r].y += xv.x * w0.y + xv.y * w1.y + xv.z * w2.y + xv.w * w3.y;
      acc[r].z += xv.x * w0.z + xv.y * w1.z + xv.z * w2.z + xv.w * w3.z;
      acc[r].w += xv.x * w0.w + xv.y * w1.w + xv.z * w2.w + xv.w * w3.w;
    }
  }

  float4 al = ((const float4*)attn_l)[tc];
  float4 ar = ((const float4*)attn_r)[tc];
#pragma unroll
  for (int r = 0; r < 4; ++r) {
    int gr = row0 + 4 * tr + r;
    if (gr < n) {
      ushort4 h;
      h.x = f32_to_bf16(acc[r].x);
      h.y = f32_to_bf16(acc[r].y);
      h.z = f32_to_bf16(acc[r].z);
      h.w = f32_to_bf16(acc[r].w);
      *(ushort4*)(ftb + (size_t)gr * 128 + tc * 4) = h;
    }
    float s1 = acc[r].x * al.x + acc[r].y * al.y + acc[r].z * al.z +
               acc[r].w * al.w;
    float s2 = acc[r].x * ar.x + acc[r].y * ar.y + acc[r].z * ar.z +
               acc[r].w * ar.w;
#pragma unroll
    for (int off = 16; off; off >>= 1) {
      s1 += __shfl_xor(s1, off);
      s2 += __shfl_xor(s2, off);
    }
    if (tc == 0 && gr < n) {
      a1[gr] = s1;
      a2[gr] = s2;
    }
  }
}

// ---------------------------------------------------------------------------
// Kernel 2: dst histogram
// ---------------------------------------------------------------------------
__global__ __launch_bounds__(256) void hist_deg(const int* __restrict__ dst,
                                                int* __restrict__ deg, int E) {
  int e = blockIdx.x * blockDim.x + threadIdx.x;
  if (e < E) atomicAdd(&deg[dst[e]], 1);
}

// ---------------------------------------------------------------------------
// Scan pipeline: deg[n] -> rowptr[n] (exclusive start offsets)
// ---------------------------------------------------------------------------
__global__ __launch_bounds__(256) void scan_partial(const int* __restrict__ deg,
                                                    int* __restrict__ part,
                                                    int n) {
  __shared__ int sd[256];
  int base = blockIdx.x * 1024;
  int s = 0;
  for (int i = threadIdx.x; i < 1024; i += 256) {
    int idx = base + i;
    s += (idx < n) ? deg[idx] : 0;
  }
  sd[threadIdx.x] = s;
  __syncthreads();
  for (int off = 128; off; off >>= 1) {
    if (threadIdx.x < off) sd[threadIdx.x] += sd[threadIdx.x + off];
    __syncthreads();
  }
  if (threadIdx.x == 0) part[blockIdx.x] = sd[0];
}

__global__ __launch_bounds__(1024) void scan_top(int* __restrict__ part,
                                                 int B) {
  __shared__ int sd[1024];
  int t = threadIdx.x;
  int mine = (t < B) ? part[t] : 0;
  sd[t] = mine;
  __syncthreads();
  for (int off = 1; off < 1024; off <<= 1) {
    int v = (t >= off) ? sd[t - off] : 0;
    __syncthreads();
    sd[t] += v;
    __syncthreads();
  }
  if (t < B) part[t] = sd[t] - mine;  // exclusive
}

__global__ __launch_bounds__(256) void scan_write(const int* __restrict__ deg,
                                                  const int* __restrict__ part,
                                                  int* __restrict__ rowptr,
                                                  int n) {
  __shared__ int tsum[256];
  int base = blockIdx.x * 1024;
  int v[4];
  int s = 0;
#pragma unroll
  for (int j = 0; j < 4; ++j) {
    int idx = base + threadIdx.x * 4 + j;
    v[j] = (idx < n) ? deg[idx] : 0;
    s += v[j];
  }
  tsum[threadIdx.x] = s;
  __syncthreads();
  for (int off = 1; off < 256; off <<= 1) {
    int t = (threadIdx.x >= (unsigned)off) ? tsum[threadIdx.x - off] : 0;
    __syncthreads();
    tsum[threadIdx.x] += t;
    __syncthreads();
  }
  int excl = tsum[threadIdx.x] - s + part[blockIdx.x];
#pragma unroll
  for (int j = 0; j < 4; ++j) {
    int idx = base + threadIdx.x * 4 + j;
    if (idx < n) {
      rowptr[idx] = excl;
      excl += v[j];
    }
  }
}

// ---------------------------------------------------------------------------
// Kernel 3: gate + scatter packed (src:17b | wq:15b) grouped by dst.
// rowptr mutates into end offsets. No z atomic — z is recomputed in the
// aggregate kernel from the very pairs it already reads.
// ---------------------------------------------------------------------------
__global__ __launch_bounds__(256) void edge_gate_scatter(
    const int* __restrict__ src, const int* __restrict__ dst,
    const float* __restrict__ a1, const float* __restrict__ a2,
    const float* __restrict__ bias, int* __restrict__ rowptr,
    unsigned* __restrict__ pairs, int E) {
  int e = blockIdx.x * blockDim.x + threadIdx.x;
  if (e >= E) return;
  int s = src[e], d = dst[e];
  float val = 1.0f;
  if (s != d) {
    float logit = (a1[s] + a2[d] + bias[0]) * BETA_INV;
    float sg = 1.0f / (1.0f + __expf(-logit));
    val = fminf(fmaxf(sg * ZMG + GAMMA_C, 0.0f), 1.0f);
  }
  unsigned wq = (unsigned)__float2int_rn(val * WQ_SCALE);
  unsigned packed = ((unsigned)s << 15) | wq;
  int pos = atomicAdd(&rowptr[d], 1);
  pairs[pos] = packed;
}

// ---------------------------------------------------------------------------
// Kernel 4: out[v] = (sum w_e * ftb[src_e]) / (sum w_e) — one wave per node.
// 16 lanes x uint4 cover one 256B bf16 row; 4 edges processed per step.
// acc[i] corresponds to output element li*8 + i (in order).
// ---------------------------------------------------------------------------
__global__ __launch_bounds__(256) void aggregate_bf16(
    const unsigned* __restrict__ pairs, const int* __restrict__ rowend,
    const ushort* __restrict__ ftb, float* __restrict__ out, int n) {
  int lane = threadIdx.x & 63;
  int node = (int)((blockIdx.x * blockDim.x + threadIdx.x) >> 6);
  if (node >= n) return;
  int e1 = rowend[node];
  int e0 = (node == 0) ? 0 : rowend[node - 1];
  int g = lane >> 4, li = lane & 15;
  float acc[8] = {0.f, 0.f, 0.f, 0.f, 0.f, 0.f, 0.f, 0.f};
  float wsum = 0.f;

  for (int base = e0; base < e1; base += 64) {
    int cnt = min(64, e1 - base);
    int sidx = 0;
    float w = 0.f;
    if (lane < cnt) {
      unsigned p = pairs[base + lane];
      sidx = (int)(p >> 15);
      w = (float)(p & 0x7fffu) * WQ_INV;
    }
    wsum += w;
    int nj = (cnt + 3) >> 2;
    for (int j = 0; j < nj; ++j) {
      int idx = 4 * j + g;
      int sj = __shfl(sidx, idx);
      float wj = __shfl(w, idx);   // wj == 0 for idx >= cnt (w zeroed)
      uint4 v = ((const uint4*)(ftb + (size_t)sj * 128))[li];
      acc[0] += wj * __uint_as_float(v.x << 16);          // elem li*8+0
      acc[1] += wj * __uint_as_float(v.x & 0xffff0000u);  // elem li*8+1
      acc[2] += wj * __uint_as_float(v.y << 16);
      acc[3] += wj * __uint_as_float(v.y & 0xffff0000u);
      acc[4] += wj * __uint_as_float(v.z << 16);
      acc[5] += wj * __uint_as_float(v.z & 0xffff0000u);
      acc[6] += wj * __uint_as_float(v.w << 16);
      acc[7] += wj * __uint_as_float(v.w & 0xffff0000u);
    }
  }
  // z = total gate sum over the node's edges (self-loop guarantees z >= 1)
#pragma unroll
  for (int off = 1; off < 64; off <<= 1) wsum += __shfl_xor(wsum, off);
  float zinv = 1.0f / wsum;
#pragma unroll
  for (int i = 0; i < 8; ++i) {
    acc[i] += __shfl_xor(acc[i], 16);
    acc[i] += __shfl_xor(acc[i], 32);
    acc[i] *= zinv;
  }
  if (lane < 16) {
    float4* op = (float4*)(out + (size_t)node * 128 + li * 8);
    op[0] = make_float4(acc[0], acc[1], acc[2], acc[3]);
    op[1] = make_float4(acc[4], acc[5], acc[6], acc[7]);
  }
}

// ---------------------------------------------------------------------------
extern "C" void kernel_launch(void* const* d_in, const int* in_sizes, int n_in,
                              void* d_out, int out_size, void* d_ws,
                              size_t ws_size, hipStream_t stream) {
  const float* x      = (const float*)d_in[0];
  const float* W      = (const float*)d_in[1];
  const float* b      = (const float*)d_in[2];
  const float* attn_l = (const float*)d_in[3];
  const float* attn_r = (const float*)d_in[4];
  const float* bias   = (const float*)d_in[5];
  const int*   src    = (const int*)d_in[6];
  const int*   dst    = (const int*)d_in[7];

  const int n = in_sizes[0] / 128;   // 100000
  const int E = in_sizes[6];         // 1700000
  const int B = (n + 1023) / 1024;

  // workspace: ftb bf16[n*128] | a1[n] | a2[n] | deg[n] | part[1024]
  //            | rowptr[n] | pairs uint[E]
  ushort* ftb      = (ushort*)d_ws;
  float*  a1       = (float*)(ftb + (size_t)n * 128);
  float*  a2       = a1 + n;
  int*    deg      = (int*)(a2 + n);
  int*    part     = deg + n;
  int*    rowptr   = part + 1024;
  unsigned* pairs  = (unsigned*)(rowptr + n);

  (void)hipMemsetAsync(deg, 0, (size_t)n * sizeof(int), stream);

  gemm_ft<<<(n + 31) / 32, 256, 0, stream>>>(x, W, b, attn_l, attn_r, ftb, a1,
                                             a2, n);
  hist_deg<<<(E + 255) / 256, 256, 0, stream>>>(dst, deg, E);
  scan_partial<<<B, 256, 0, stream>>>(deg, part, n);
  scan_top<<<1, 1024, 0, stream>>>(part, B);
  scan_write<<<B, 256, 0, stream>>>(deg, part, rowptr, n);
  edge_gate_scatter<<<(E + 255) / 256, 256, 0, stream>>>(src, dst, a1, a2, bias,
                                                         rowptr, pairs, E);
  aggregate_bf16<<<((size_t)n * 64 + 255) / 256, 256, 0, stream>>>(
      pairs, rowptr, ftb, (float*)d_out, n);
}